// Round 16
// baseline (423.289 us; speedup 1.0000x reference)
//
#include <hip/hip_runtime.h>
#include <hip/hip_bf16.h>

// B=8, S=2048, D=1024, O=1024
// attn = (q Wq)(k Wk)^T = q G k^T, G = Wq Wk^T (Wk-projection absorbed).
// vp = k@Wv ; w = softmax(attn,-1) ; context = w^T @ vp ;
// out = concat([q, context], -1)  fp32 [B,S,2048]
//
// Pipeline: Gt = Wk_h @ Wq_h^T (8-way K-split + reduce, once);
// qG = qpack@Gt^T, vpT = kpack@Wtv^T (fused y=2); attnT = kpack@qG^T ->
// f16 e + per-64-row partials; merge -> f16 scales; PV applies scales
// in-register (CM_PVS).
//
// GEMM r16 = faithful m97 structure (874-912 TF documented): 128x128 tile,
// BK=32, 4 waves (2x2), 16x16x32 f16 MFMA, SINGLE-buffered 16 KiB LDS,
// plain __syncthreads (compiler schedules all waitcnts), no inline asm,
// no launch-bounds reg cap -> ~3 blocks/CU; cross-block overlap (m114)
// covers the barrier drain. BK=32 64B rows + 16x16 frags are bank-optimal
// (8 lanes/slot) with LINEAR LDS - no swizzle anywhere.
// r8-r15 established: my explicit-asm 2/4-phase structures are pinned at
// ~31% regardless of barriers/pins/prefetch/occupancy - abandoned.

typedef __attribute__((ext_vector_type(4))) float f32x4;
typedef _Float16 f16;
typedef __attribute__((ext_vector_type(8))) _Float16 f16x8;
typedef __attribute__((ext_vector_type(4))) _Float16 f16x4;

#define LOG2E 1.4426950408889634f

#define CM_F32     0
#define CM_F16     1
#define CM_ATTN    4
#define CM_PROJ2   5
#define CM_PVS     6

#define GLD(SRC, DST) \
    __builtin_amdgcn_global_load_lds( \
        (const __attribute__((address_space(1))) void*)(SRC), \
        (__attribute__((address_space(3))) void*)(DST), 16, 0, 0)

// CM_PROJ2: blockIdx.y 0 -> qG = A@B^T (f16, ld 1024); 1 -> A+=M*1024
// (kpack), B+=1M (Wtv), vpT via pm (stride M). CM_PVS: ps = f16 scale
// table [z][32][2048].
template<int CMODE>
__global__ __launch_bounds__(256)
void gemm128(const f16* __restrict__ A, const f16* __restrict__ B,
             void* __restrict__ Cv,
             int M, int N, int K, int lda, int ldb, int ldc,
             long az, long bz, long cz,
             float* __restrict__ pm, float* __restrict__ ps)
{
    __shared__ __align__(16) char smem[24576];   // As 8K | Bs 8K | scales 8K
    f16* As = (f16*)smem;
    f16* Bs = (f16*)(smem + 8192);
    f16* Sc = (f16*)(smem + 16384);

    const int z = blockIdx.z;
    const char* Ab;
    const char* Bb;
    if (CMODE == CM_PROJ2) {
        const int y = blockIdx.y;
        Ab = (const char*)(A + (y ? (long)M * 1024 : 0));
        Bb = (const char*)(B + (long)y * 1024 * 1024);
    } else {
        Ab = (const char*)(A + z * az);
        Bb = (const char*)(B + z * bz);
    }

    // XCD-aware swizzle (all launches have nwg % 8 == 0)
    const int nbx = N >> 7;
    int wg = blockIdx.x;
    const int nwg = gridDim.x;
    if ((nwg & 7) == 0) wg = (wg & 7) * (nwg >> 3) + (wg >> 3);
    const int bm = (wg / nbx) << 7;
    const int bn = (wg % nbx) << 7;

    const int tid = threadIdx.x;
    const int wave = tid >> 6;          // 0..3
    const int lane = tid & 63;
    const int r16 = lane & 15;
    const int h4 = lane >> 4;           // 0..3 (k-slot / row-quad)
    const int wm = wave >> 1;           // rows wm*64..+64
    const int wn = wave & 1;            // cols wn*64..+64

    // staging constants (linear: LDS byte offset == tid*16 per 4KB pass)
    const int srow = tid >> 2;          // 0..63
    const int skc = (tid & 3) * 8;      // k elems 0,8,16,24

    f32x4 acc[4][4];
    #pragma unroll
    for (int mt = 0; mt < 4; ++mt)
        #pragma unroll
        for (int nt = 0; nt < 4; ++nt)
            acc[mt][nt] = f32x4{0.f, 0.f, 0.f, 0.f};

    if (CMODE == CM_PVS) {
        // stage 2 contiguous 64-row scale groups (8 KB) for rows bm..bm+127
        const char* gsc = (const char*)ps +
            (((long)z * 32 + (bm >> 6)) * 2048) * 2 + lane * 16;
        GLD(gsc + wave * 1024, (char*)smem + 16384 + wave * 1024);
        GLD(gsc + 4096 + wave * 1024, (char*)smem + 20480 + wave * 1024);
    }

    const int ntk = K >> 5;
    for (int t = 0; t < ntk; ++t) {
        __syncthreads();                // prior tile's ds_reads complete
        const int k0 = t * 32 + skc;
        GLD(Ab + ((long)(bm + srow) * lda + k0) * 2,
            (char*)smem + wave * 1024);
        GLD(Ab + ((long)(bm + 64 + srow) * lda + k0) * 2,
            (char*)smem + 4096 + wave * 1024);
        GLD(Bb + ((long)(bn + srow) * ldb + k0) * 2,
            (char*)smem + 8192 + wave * 1024);
        GLD(Bb + ((long)(bn + 64 + srow) * ldb + k0) * 2,
            (char*)smem + 12288 + wave * 1024);
        __syncthreads();                // compiler drains DMA (vmcnt 0)

        f16x8 a4[4], b4[4];
        #pragma unroll
        for (int mt = 0; mt < 4; ++mt)
            a4[mt] = *(const f16x8*)(As + (wm * 64 + mt * 16 + r16) * 32 + h4 * 8);
        #pragma unroll
        for (int nt = 0; nt < 4; ++nt)
            b4[nt] = *(const f16x8*)(Bs + (wn * 64 + nt * 16 + r16) * 32 + h4 * 8);
        if (CMODE == CM_PVS) {
            // A elem j <-> q = t*32 + h4*8 + j; group = (bm>>6)+wm (wave-const)
            const f16x8 sv = *(const f16x8*)(Sc + wm * 2048 + t * 32 + h4 * 8);
            #pragma unroll
            for (int mt = 0; mt < 4; ++mt) a4[mt] *= sv;
        }
        #pragma unroll
        for (int mt = 0; mt < 4; ++mt)
            #pragma unroll
            for (int nt = 0; nt < 4; ++nt)
                acc[mt][nt] = __builtin_amdgcn_mfma_f32_16x16x32_f16(
                    a4[mt], b4[nt], acc[mt][nt], 0, 0, 0);
    }

    // ---- epilogue: 16x16 D mapping col=lane&15, row=(lane>>4)*4+r ----
    if (CMODE == CM_ATTN) {
        f16* E = (f16*)Cv + z * cz;
        #pragma unroll
        for (int nt = 0; nt < 4; ++nt) {
            float Mx = -3.4e38f;
            #pragma unroll
            for (int mt = 0; mt < 4; ++mt)
                #pragma unroll
                for (int r = 0; r < 4; ++r)
                    Mx = fmaxf(Mx, acc[mt][nt][r]);
            Mx = fmaxf(Mx, __shfl_xor(Mx, 16, 64));
            Mx = fmaxf(Mx, __shfl_xor(Mx, 32, 64));
            float Sm = 0.f;
            #pragma unroll
            for (int mt = 0; mt < 4; ++mt)
                #pragma unroll
                for (int r = 0; r < 4; ++r) {
                    const float e = exp2f((acc[mt][nt][r] - Mx) * LOG2E);
                    acc[mt][nt][r] = e;
                    Sm += e;
                }
            Sm += __shfl_xor(Sm, 16, 64);
            Sm += __shfl_xor(Sm, 32, 64);
            const int col = bn + wn * 64 + nt * 16 + r16;
            #pragma unroll
            for (int mt = 0; mt < 4; ++mt) {
                const int row0 = bm + wm * 64 + mt * 16 + h4 * 4;
                #pragma unroll
                for (int r = 0; r < 4; ++r)
                    E[(long)(row0 + r) * ldc + col] = (f16)acc[mt][nt][r];
            }
            if (lane < 16) {
                // one 64-row group per wave: (bm>>6)+wm in [0,32)
                const long pidx = ((long)z * 32 + (bm >> 6) + wm) * N + col;
                pm[pidx] = Mx * LOG2E;   // log2 domain
                ps[pidx] = Sm;
            }
        }
        return;
    }

    #pragma unroll
    for (int mt = 0; mt < 4; ++mt) {
        #pragma unroll
        for (int nt = 0; nt < 4; ++nt) {
            const int row0 = bm + wm * 64 + mt * 16 + h4 * 4;
            const int col = bn + wn * 64 + nt * 16 + r16;
            if (CMODE == CM_F32 || CMODE == CM_PVS) {
                float* C = (float*)Cv + z * cz;
                #pragma unroll
                for (int r = 0; r < 4; ++r)
                    C[(long)(row0 + r) * ldc + col] = acc[mt][nt][r];
            } else if (CMODE == CM_F16) {
                f16* C = (f16*)Cv + z * cz;
                #pragma unroll
                for (int r = 0; r < 4; ++r)
                    C[(long)(row0 + r) * ldc + col] = (f16)acc[mt][nt][r];
            } else { // CM_PROJ2
                if (blockIdx.y == 0) {
                    f16* C = (f16*)Cv;
                    #pragma unroll
                    for (int r = 0; r < 4; ++r)
                        C[(long)(row0 + r) * 1024 + col] = (f16)acc[mt][nt][r];
                } else {
                    f16* C = (f16*)pm;   // vpT [1024][M]
                    f16x4 v;
                    #pragma unroll
                    for (int r = 0; r < 4; ++r) v[r] = (f16)acc[mt][nt][r];
                    *(f16x4*)(C + (long)col * M + row0) = v;
                }
            }
        }
    }
}

// ---------------------------------------------------------------------------
// fused cast: q rows -> f16 + fp32 copy into out[:,0:1024]; k rows -> f16
// ---------------------------------------------------------------------------
__global__ __launch_bounds__(256)
void pack_cast_qk(const float* __restrict__ qin, const float* __restrict__ kin,
                  f16* __restrict__ qp, f16* __restrict__ kp,
                  float* __restrict__ oq, long nquads)
{
    const long i = (long)blockIdx.x * 256 + threadIdx.x;
    if (i >= 2 * nquads) return;
    const int isK = (i >= nquads);
    const long j = isK ? i - nquads : i;
    const long row = j >> 8;
    const int c = (int)(j & 255) * 4;
    const float4 v = isK ? *(const float4*)(kin + row * 1024 + c)
                         : *(const float4*)(qin + row * 1024 + c);
    f16x4 h;
    h[0] = (f16)v.x; h[1] = (f16)v.y; h[2] = (f16)v.z; h[3] = (f16)v.w;
    if (isK) {
        *(f16x4*)(kp + row * 1024 + c) = h;
    } else {
        *(float4*)(oq + row * 2048 + c) = v;
        *(f16x4*)(qp + row * 1024 + c) = h;
    }
}

// plain fp32 [R,1024] -> f16 [R,1024]
__global__ __launch_bounds__(256)
void cast_f16(const float* __restrict__ in, f16* __restrict__ outp, long nquads)
{
    const long i = (long)blockIdx.x * 256 + threadIdx.x;
    if (i >= nquads) return;
    const long row = i >> 8;
    const int c = (int)(i & 255) * 4;
    const float4 v = *(const float4*)(in + row * 1024 + c);
    f16x4 h;
    h[0] = (f16)v.x; h[1] = (f16)v.y; h[2] = (f16)v.z; h[3] = (f16)v.w;
    *(f16x4*)(outp + row * 1024 + c) = h;
}

// ---------------------------------------------------------------------------
// W [1024 d][1024 o] fp32 -> Wt [1024 o][1024 d] f16 (transpose + cast)
// ---------------------------------------------------------------------------
__global__ __launch_bounds__(256)
void pack_W_T(const float* __restrict__ W, f16* __restrict__ Wt)
{
    __shared__ float tile[64][65];
    const int d0 = blockIdx.y * 64, o0 = blockIdx.x * 64;
    const int t = threadIdx.x;
    const int rr = t >> 4, c4 = (t & 15) * 4;
    #pragma unroll
    for (int it = 0; it < 4; ++it) {
        const int r = rr + it * 16;
        const float4 v = *(const float4*)(W + (long)(d0 + r) * 1024 + o0 + c4);
        tile[r][c4] = v.x; tile[r][c4 + 1] = v.y;
        tile[r][c4 + 2] = v.z; tile[r][c4 + 3] = v.w;
    }
    __syncthreads();
    #pragma unroll
    for (int it = 0; it < 4; ++it) {
        const int orow = rr + it * 16;
        f16x4 h;
        #pragma unroll
        for (int j = 0; j < 4; ++j) h[j] = (f16)tile[c4 + j][orow];
        *(f16x4*)(Wt + (long)(o0 + orow) * 1024 + d0 + c4) = h;
    }
}

// ---------------------------------------------------------------------------
// reduce 8 f32 partials [8][1024*1024] -> f16 Gt[1024*1024]
// ---------------------------------------------------------------------------
__global__ __launch_bounds__(256)
void gt_reduce(const float* __restrict__ P, f16* __restrict__ Gt, long nquads)
{
    const long i = (long)blockIdx.x * 256 + threadIdx.x;
    if (i >= nquads) return;
    float4 s = *(const float4*)(P + i * 4);
    #pragma unroll
    for (int z = 1; z < 8; ++z) {
        const float4 v = *(const float4*)(P + (long)z * 1048576 + i * 4);
        s.x += v.x; s.y += v.y; s.z += v.z; s.w += v.w;
    }
    f16x4 h;
    h[0] = (f16)s.x; h[1] = (f16)s.y; h[2] = (f16)s.z; h[3] = (f16)s.w;
    *(f16x4*)(Gt + i * 4) = h;
}

// ---------------------------------------------------------------------------
// merge 32 per-group partials -> f16 scale[z][32][2048] = exp2(pm - L)
// ---------------------------------------------------------------------------
__global__ __launch_bounds__(256)
void softmax_merge32(const float* __restrict__ pm, const float* __restrict__ ps,
                     f16* __restrict__ scale, int nq)
{
    const int idx = blockIdx.x * 256 + threadIdx.x;
    if (idx >= nq) return;
    const int z = idx >> 11, q = idx & 2047;
    const float* pmz = pm + ((long)z * 32) * 2048 + q;
    const float* psz = ps + ((long)z * 32) * 2048 + q;
    float mx = -3.4e38f;
    #pragma unroll
    for (int j = 0; j < 32; ++j) mx = fmaxf(mx, pmz[j * 2048]);
    float s = 0.f;
    #pragma unroll
    for (int j = 0; j < 32; ++j)
        s += psz[j * 2048] * exp2f(pmz[j * 2048] - mx);
    const float L = mx + log2f(s);
    f16* sc = scale + ((long)z * 32) * 2048 + q;
    #pragma unroll
    for (int j = 0; j < 32; ++j)
        sc[j * 2048] = (f16)exp2f(pmz[j * 2048] - L);
}

// ---------------------------------------------------------------------------
__global__ __launch_bounds__(256)
void copy_q_kernel(const float* __restrict__ q, float* __restrict__ out, long n4)
{
    const long idx = (long)blockIdx.x * 256 + threadIdx.x;
    if (idx >= n4) return;
    const long row = idx >> 8;
    const long c4 = idx & 255;
    *(float4*)(&out[row * 2048 + c4 * 4]) =
        *(const float4*)(&q[row * 1024 + c4 * 4]);
}

// ===========================================================================
// fp32 fallback for small workspaces
// ===========================================================================
#define BM 64
#define BN 64
#define BKF 16
template<int opA, int opB>
__global__ __launch_bounds__(256)
void sgemm(const float* __restrict__ A, const float* __restrict__ B,
           float* __restrict__ C,
           int M, int N, int K, int lda, int ldb, int ldc)
{
    __shared__ float As[BKF][BM];
    __shared__ float Bs[BKF][BN];
    const int tid = threadIdx.x;
    const int tx = tid & 15, ty = tid >> 4;
    const int bm = blockIdx.y * BM, bn = blockIdx.x * BN;
    float acc[4][4] = {};
    for (int k0 = 0; k0 < K; k0 += BKF) {
        if (opA == 0) {
            const int row = tid >> 2, kq = (tid & 3) * 4;
            const float4 v = *(const float4*)(A + (long)(bm + row) * lda + (k0 + kq));
            As[kq + 0][row] = v.x; As[kq + 1][row] = v.y;
            As[kq + 2][row] = v.z; As[kq + 3][row] = v.w;
        } else {
            const int kk = tid >> 4, mq = (tid & 15) * 4;
            *(float4*)(&As[kk][mq]) =
                *(const float4*)(A + (long)(k0 + kk) * lda + (bm + mq));
        }
        if (opB == 0) {
            const int kk = tid >> 4, nq = (tid & 15) * 4;
            *(float4*)(&Bs[kk][nq]) =
                *(const float4*)(B + (long)(k0 + kk) * ldb + (bn + nq));
        } else {
            const int row = tid >> 2, kq = (tid & 3) * 4;
            const float4 v = *(const float4*)(B + (long)(bn + row) * ldb + (k0 + kq));
            Bs[kq + 0][row] = v.x; Bs[kq + 1][row] = v.y;
            Bs[kq + 2][row] = v.z; Bs[kq + 3][row] = v.w;
        }
        __syncthreads();
        #pragma unroll
        for (int kk = 0; kk < BKF; ++kk) {
            const float4 a = *(const float4*)(&As[kk][ty * 4]);
            const float4 b = *(const float4*)(&Bs[kk][tx * 4]);
            const float av[4] = {a.x, a.y, a.z, a.w};
            const float bv[4] = {b.x, b.y, b.z, b.w};
            #pragma unroll
            for (int i = 0; i < 4; ++i)
                #pragma unroll
                for (int j = 0; j < 4; ++j)
                    acc[i][j] += av[i] * bv[j];
        }
        __syncthreads();
    }
    #pragma unroll
    for (int i = 0; i < 4; ++i) {
        const float4 v = make_float4(acc[i][0], acc[i][1], acc[i][2], acc[i][3]);
        *(float4*)(&C[(long)(bm + ty * 4 + i) * ldc + (bn + tx * 4)]) = v;
    }
}

__device__ __forceinline__ float wave_reduce_max(float v) {
    #pragma unroll
    for (int off = 1; off < 64; off <<= 1)
        v = fmaxf(v, __shfl_xor(v, off, 64));
    return v;
}
__device__ __forceinline__ float wave_reduce_sum(float v) {
    #pragma unroll
    for (int off = 1; off < 64; off <<= 1)
        v += __shfl_xor(v, off, 64);
    return v;
}

__global__ __launch_bounds__(256)
void softmax_rows2048(float* __restrict__ X)
{
    float* x = X + (long)blockIdx.x * 2048;
    const int tid = threadIdx.x;
    float4 v0 = *(const float4*)(&x[tid * 4]);
    float4 v1 = *(const float4*)(&x[1024 + tid * 4]);
    float m = fmaxf(fmaxf(fmaxf(v0.x, v0.y), fmaxf(v0.z, v0.w)),
                    fmaxf(fmaxf(v1.x, v1.y), fmaxf(v1.z, v1.w)));
    m = wave_reduce_max(m);
    __shared__ float sm[4];
    __shared__ float ss[4];
    const int wid = tid >> 6;
    if ((tid & 63) == 0) sm[wid] = m;
    __syncthreads();
    m = fmaxf(fmaxf(sm[0], sm[1]), fmaxf(sm[2], sm[3]));
    v0.x = expf(v0.x - m); v0.y = expf(v0.y - m);
    v0.z = expf(v0.z - m); v0.w = expf(v0.w - m);
    v1.x = expf(v1.x - m); v1.y = expf(v1.y - m);
    v1.z = expf(v1.z - m); v1.w = expf(v1.w - m);
    float s = (v0.x + v0.y + v0.z + v0.w) + (v1.x + v1.y + v1.z + v1.w);
    s = wave_reduce_sum(s);
    if ((tid & 63) == 0) ss[wid] = s;
    __syncthreads();
    s = ss[0] + ss[1] + ss[2] + ss[3];
    const float inv = 1.0f / s;
    v0.x *= inv; v0.y *= inv; v0.z *= inv; v0.w *= inv;
    v1.x *= inv; v1.y *= inv; v1.z *= inv; v1.w *= inv;
    *(float4*)(&x[tid * 4]) = v0;
    *(float4*)(&x[1024 + tid * 4]) = v1;
}

static void fallback_fp32(const float* q, const float* k, const float* Wq,
                          const float* Wk, const float* Wv, float* out,
                          void* d_ws, hipStream_t stream)
{
    const int S = 2048, D = 1024, O = 1024, B = 8;
    float* qp = (float*)d_ws;
    float* kp = qp + (size_t)S * O;
    float* vp = kp + (size_t)S * O;
    float* attn = vp + (size_t)S * O;
    const long n4 = (long)B * S * D / 4;
    copy_q_kernel<<<dim3((n4 + 255) / 256), 256, 0, stream>>>(q, out, n4);
    const dim3 blk(256);
    const dim3 gproj(O / BN, S / BM), gattn(S / BN, S / BM), gctx(O / BN, S / BM);
    for (int b = 0; b < B; ++b) {
        const float* qb = q + (size_t)b * S * D;
        const float* kb = k + (size_t)b * S * D;
        float* outc = out + (size_t)b * S * 2048 + D;
        sgemm<0, 0><<<gproj, blk, 0, stream>>>(qb, Wq, qp, S, O, D, D, O, O);
        sgemm<0, 0><<<gproj, blk, 0, stream>>>(kb, Wk, kp, S, O, D, D, O, O);
        sgemm<0, 0><<<gproj, blk, 0, stream>>>(kb, Wv, vp, S, O, D, D, O, O);
        sgemm<0, 1><<<gattn, blk, 0, stream>>>(qp, kp, attn, S, S, O, O, O, S);
        softmax_rows2048<<<dim3(S), blk, 0, stream>>>(attn);
        sgemm<1, 0><<<gctx, blk, 0, stream>>>(attn, vp, outc, S, O, S, S, O, 2048);
    }
}

// ===========================================================================
extern "C" void kernel_launch(void* const* d_in, const int* in_sizes, int n_in,
                              void* d_out, int out_size, void* d_ws, size_t ws_size,
                              hipStream_t stream)
{
    const float* q  = (const float*)d_in[0];
    const float* k  = (const float*)d_in[1];
    const float* Wq = (const float*)d_in[2];
    const float* Wk = (const float*)d_in[3];
    const float* Wv = (const float*)d_in[4];
    float* out = (float*)d_out;

    const int B = 8, S = 2048;

    auto need = [](int g) -> size_t {
        const size_t fixed = ((size_t)1024 * 1024 * 2) * 4
                           + (size_t)8 * 1024 * 1024 * 4;
        const size_t pkA = (size_t)g * 2048 * 1024 * 2;
        const size_t vpT = (size_t)1024 * g * 2048 * 2;
        const size_t aw  = (size_t)g * 2048 * 2048 * 2;
        const size_t pp  = 2 * (size_t)g * 32 * 2048 * 4 + (size_t)g * 32 * 2048 * 2;
        return fixed + 3 * pkA + vpT + aw + pp + 32 * 256;
    };
    int g = 0;
    for (int cand : {8, 4, 2, 1})
        if (need(cand) <= ws_size) { g = cand; break; }
    if (g == 0) { fallback_fp32(q, k, Wq, Wk, Wv, out, d_ws, stream); return; }

    char* p = (char*)d_ws;
    auto carve = [&](size_t bytes) {
        char* r = p;
        p += (bytes + 255) & ~(size_t)255;
        return r;
    };
    // Gt & Wtv contiguous (B pair for CM_PROJ2); qpack & kpack contiguous.
    f16* Gt   = (f16*)carve((size_t)1024 * 1024 * 2);
    f16* Wtv  = (f16*)carve((size_t)1024 * 1024 * 2);
    f16* Wq_h = (f16*)carve((size_t)1024 * 1024 * 2);
    f16* Wk_h = (f16*)carve((size_t)1024 * 1024 * 2);
    float* Gp = (float*)carve((size_t)8 * 1024 * 1024 * 4);
    const size_t pkAB = (size_t)g * 2048 * 1024 * 2;
    f16* qpack  = (f16*)carve(pkAB);
    f16* kpack  = (f16*)carve(pkAB);
    f16* qG     = (f16*)carve(pkAB);
    f16* vpT    = (f16*)carve((size_t)1024 * g * 2048 * 2);
    f16* attn_w = (f16*)carve((size_t)g * 2048 * 2048 * 2);
    float* pmb  = (float*)carve((size_t)g * 32 * 2048 * 4);
    float* psb  = (float*)carve((size_t)g * 32 * 2048 * 4);
    f16* scb    = (f16*)carve((size_t)g * 32 * 2048 * 2);

    const dim3 blk(256);

    // --- once: Wv transpose, Wq/Wk casts, Gt = Wk_h @ Wq_h^T (8-way K-split)
    pack_W_T<<<dim3(16, 16), blk, 0, stream>>>(Wv, Wtv);
    cast_f16<<<dim3(1024), blk, 0, stream>>>(Wq, Wq_h, 1024 * 256);
    cast_f16<<<dim3(1024), blk, 0, stream>>>(Wk, Wk_h, 1024 * 256);
    gemm128<CM_F32><<<dim3(64, 1, 8), blk, 0, stream>>>(
        Wk_h, Wq_h, Gp, 1024, 1024, 128, 1024, 1024, 1024,
        128, 128, (long)1024 * 1024, nullptr, nullptr);
    gt_reduce<<<dim3(1024), blk, 0, stream>>>(Gp, Gt, 1024 * 256);

    const int Mg = g * 2048;
    const long zSS = (long)2048 * 2048;
    const long zSD = (long)2048 * 1024;

    for (int gi = 0; gi < B / g; ++gi) {
        const float* qg = q + (size_t)gi * Mg * 1024;
        const float* kg = k + (size_t)gi * Mg * 1024;
        float* outq = out + (size_t)gi * Mg * 2048;

        const long nquads = (long)Mg * 256;
        pack_cast_qk<<<dim3((2 * nquads + 255) / 256), blk, 0, stream>>>(
            qg, kg, qpack, kpack, outq, nquads);

        // fused: y=0 -> qG = qpack@Gt^T ; y=1 -> vpT = kpack@Wtv^T
        const dim3 g1((1024 / 128) * (Mg / 128), 2, 1);
        gemm128<CM_PROJ2><<<g1, blk, 0, stream>>>(
            qpack, Gt, qG, Mg, 1024, 1024, 1024, 1024, 1024, 0, 0, 0,
            (float*)vpT, nullptr);

        // attnT = kpack @ qG^T per z -> f16 e + per-64-row partials
        const dim3 g2((2048 / 128) * (2048 / 128), 1, g);
        gemm128<CM_ATTN><<<g2, blk, 0, stream>>>(
            kpack, qG, attn_w, 2048, 2048, 1024, 1024, 1024, 2048,
            zSD, zSD, zSS, pmb, psb);

        // merge partials -> f16 scale table
        const int nq = g * 2048;
        softmax_merge32<<<dim3((nq + 255) / 256), blk, 0, stream>>>(pmb, psb, scb, nq);

        // context = (e*scale) @ vpT^T -> out cols 1024..2047
        float* outg = out + (size_t)gi * Mg * 2048 + 1024;
        const dim3 g3((1024 / 128) * (2048 / 128), 1, g);
        gemm128<CM_PVS><<<g3, blk, 0, stream>>>(
            attn_w, vpT, outg, 2048, 1024, 2048, 2048, Mg, 2048,
            zSS, 2048, zSS, nullptr, (float*)scb);
    }
}

// Round 17
// 348.218 us; speedup vs baseline: 1.2156x; 1.2156x over previous
//
#include <hip/hip_runtime.h>
#include <hip/hip_bf16.h>

// B=8, S=2048, D=1024, O=1024
// attn = (q Wq)(k Wk)^T = q G k^T, G = Wq Wk^T  (Wk-projection absorbed).
// vp = k@Wv ; w = softmax(attn,-1) ; context = w^T @ vp ;
// out = concat([q, context], -1)  fp32 [B,S,2048]
//
// Pipeline: Gt = Wk_h @ Wq_h^T (8-way K-split + reduce, once);
// qG = qpack @ Gt^T ; vpT = kpack @ Wtv^T (fused grid.y=2);
// attnT = kpack @ qG^T -> f16 e + per-128-row partials; merge -> f16 scales;
// PV multiplies A-frags by scales in-register (CM_PVS).
//
// GEMM: 256x256 tile, BK=64, 8 waves, 32x32x16 f16 MFMA, 2 phases/K-tile,
// counted vmcnt(4), setprio, XCD swizzle, swizzled LDS, launch_bounds(512,2).
// r8-r16 session ledger: schedule variants (barrier count, sched pins,
// prefetch depth, STAGE placement) all NULL; occupancy variants ((512,4)
// spill r9; 128^2 dbuf r12; m97-style single-buf r16) all REGRESSED.
// This r15 configuration is the empirical best: 347.9 us.

typedef __attribute__((ext_vector_type(4))) float f32x4;
typedef __attribute__((ext_vector_type(16))) float f32x16;
typedef _Float16 f16;
typedef __attribute__((ext_vector_type(8))) _Float16 f16x8;
typedef __attribute__((ext_vector_type(4))) _Float16 f16x4;

#define LOG2E 1.4426950408889634f

#define CM_F32     0
#define CM_F16     1
#define CM_F16T    3
#define CM_ATTN    4
#define CM_PROJ2   5
#define CM_PVS     6

#define STAGE(WHICH, KS, KT, BO) do { \
    const char* _gb = (WHICH) ? Bb : Ab; \
    const int _ld = (WHICH) ? ldb : lda; \
    const long _r = (WHICH) ? (long)(bn + srow0) : (long)(bm + srow0); \
    const int _k0 = (KT) * 64 + (KS) * 32 + sh8; \
    char* _dst = (char*)smem + (BO) + (WHICH) * 32768 + (KS) * 16384 + wave * 1024; \
    const char* _g0 = _gb + ((_r * _ld + _k0) << 1); \
    const char* _g1 = _gb + (((_r + 128) * _ld + _k0) << 1); \
    __builtin_amdgcn_global_load_lds((const __attribute__((address_space(1))) void*)_g0, \
        (__attribute__((address_space(3))) void*)_dst, 16, 0, 0); \
    __builtin_amdgcn_global_load_lds((const __attribute__((address_space(1))) void*)_g1, \
        (__attribute__((address_space(3))) void*)(_dst + 8192), 16, 0, 0); \
} while (0)

// One phase: K-half KS, both k-steps. 12 ds_read_b128 (+2 scale if PVS) ->
// [PVS scale-mul] -> barrier -> {STAGE gloads + 16 MFMA} -> VM -> barrier.
#define GPHASE2(KS, STAGE_CODE, VM) do { \
    f16x8 af[2][4], bb[2][2], sv[2]; \
    _Pragma("unroll") \
    for (int s = 0; s < 2; ++s) { \
        _Pragma("unroll") \
        for (int mt = 0; mt < 4; ++mt) \
            af[s][mt] = *(const f16x8*)(smem + \
                ((bufo + (KS) * 16384 + abase[mt]) ^ (s << 5))); \
        _Pragma("unroll") \
        for (int nt = 0; nt < 2; ++nt) \
            bb[s][nt] = *(const f16x8*)(smem + \
                ((bufo + (KS) * 16384 + bbase[nt]) ^ (s << 5))); \
        if (CMODE == CM_PVS) \
            sv[s] = *(const f16x8*)(smem + 131072 + wm * 4096 + \
                t * 128 + (KS) * 64 + s * 32 + (h5 << 4)); \
    } \
    if (CMODE == CM_PVS) { \
        _Pragma("unroll") \
        for (int s = 0; s < 2; ++s) \
            _Pragma("unroll") \
            for (int mt = 0; mt < 4; ++mt) \
                af[s][mt] *= sv[s]; \
    } \
    __builtin_amdgcn_s_barrier(); \
    __builtin_amdgcn_s_setprio(1); \
    STAGE_CODE; \
    _Pragma("unroll") \
    for (int s = 0; s < 2; ++s) \
        _Pragma("unroll") \
        for (int mt = 0; mt < 4; ++mt) \
            _Pragma("unroll") \
            for (int nt = 0; nt < 2; ++nt) \
                acc[mt][nt] = __builtin_amdgcn_mfma_f32_32x32x16_f16( \
                    af[s][mt], bb[s][nt], acc[mt][nt], 0, 0, 0); \
    __builtin_amdgcn_s_setprio(0); \
    VM; \
    __builtin_amdgcn_s_barrier(); \
} while (0)

// CM_PROJ2: blockIdx.y 0 -> qG = A@B^T (f16, ldc=1024); 1 -> vpT via pm
// (A offset M*1024 = kpack; B offset 1M = Wtv). CM_PVS: ps = f16 scale table.
template<int CMODE>
__global__ __launch_bounds__(512, 2)
void gemm256(const f16* __restrict__ A, const f16* __restrict__ B,
             void* __restrict__ Cv,
             int M, int N, int K, int lda, int ldb, int ldc,
             long az, long bz, long cz,
             float* __restrict__ pm, float* __restrict__ ps)
{
    __shared__ __align__(16) char smem[139264];   // 128K buffers + 8K scales

    const int z = blockIdx.z;
    const char* Ab;
    const char* Bb;
    if (CMODE == CM_PROJ2) {
        const int y = blockIdx.y;
        Ab = (const char*)(A + (y ? (long)M * 1024 : 0));
        Bb = (const char*)(B + (long)y * 1024 * 1024);
    } else {
        Ab = (const char*)(A + z * az);
        Bb = (const char*)(B + z * bz);
    }

    // XCD-aware swizzle (all launches have nwg % 8 == 0)
    const int nbx = N >> 8;
    int wg = blockIdx.x;
    const int nwg = gridDim.x;
    if ((nwg & 7) == 0) wg = (wg & 7) * (nwg >> 3) + (wg >> 3);
    const int bm = (wg / nbx) << 8;
    const int bn = (wg % nbx) << 8;

    const int tid = threadIdx.x;
    const int wave = tid >> 6;
    const int lane = tid & 63;
    const int l31 = lane & 31;
    const int h5 = lane >> 5;
    const int wm = wave >> 2;
    const int wn = wave & 3;

    const int f3 = (l31 ^ (l31 >> 2)) & 3;
    const int sl = ((h5 ^ f3) << 4);
    int abase[4], bbase[2];
    #pragma unroll
    for (int mt = 0; mt < 4; ++mt)
        abase[mt] = (wm * 128 + mt * 32 + l31) * 64 + sl;
    #pragma unroll
    for (int nt = 0; nt < 2; ++nt)
        bbase[nt] = 32768 + (wn * 64 + nt * 32 + l31) * 64 + sl;

    const int srow0 = tid >> 2;
    const int sh8 = ((tid ^ (tid >> 2) ^ (tid >> 4)) & 3) * 8;

    f32x16 acc[4][2];
    #pragma unroll
    for (int mt = 0; mt < 4; ++mt)
        #pragma unroll
        for (int nt = 0; nt < 2; ++nt)
            acc[mt][nt] = (f32x16)(0.f);

    const int nt_k = K >> 6;

    {
        if (CMODE == CM_PVS) {
            const char* gsc = (const char*)ps +
                (((long)z * 16 + (bm >> 7)) * 2048) * 2 + tid * 16;
            __builtin_amdgcn_global_load_lds(
                (const __attribute__((address_space(1))) void*)gsc,
                (__attribute__((address_space(3))) void*)
                    ((char*)smem + 131072 + wave * 1024), 16, 0, 0);
        }
        const int t1p = (nt_k > 1) ? 1 : 0;
        STAGE(0, 0, 0, 0);
        STAGE(1, 0, 0, 0);
        STAGE(0, 1, 0, 0);
        STAGE(1, 1, 0, 0);
        STAGE(0, 0, t1p, 65536);
        STAGE(1, 0, t1p, 65536);
        asm volatile("s_waitcnt vmcnt(4)" ::: "memory");
        __builtin_amdgcn_s_barrier();
    }

    for (int t = 0; t < nt_k; ++t) {
        const int bufo = (t & 1) << 16;
        const int nbo = bufo ^ 65536;
        const int t1 = (t + 1 < nt_k) ? t + 1 : nt_k - 1;
        const int t2 = (t + 2 < nt_k) ? t + 2 : nt_k - 1;
        GPHASE2(0, { STAGE(0, 1, t1, nbo); STAGE(1, 1, t1, nbo); }, );
        GPHASE2(1, { STAGE(0, 0, t2, bufo); STAGE(1, 0, t2, bufo); },
                asm volatile("s_waitcnt vmcnt(4)" ::: "memory"));
    }
    asm volatile("s_waitcnt vmcnt(0)" ::: "memory");

    // ---- epilogue: 32x32 D mapping col=lane&31, row=(reg&3)+4*(lane>>5)+8*(reg>>2)
    if (CMODE == CM_ATTN) {
        f16* E = (f16*)Cv + z * cz;
        #pragma unroll
        for (int nt = 0; nt < 2; ++nt) {
            float Mx = -3.4e38f;
            #pragma unroll
            for (int mt = 0; mt < 4; ++mt)
                #pragma unroll
                for (int r = 0; r < 16; ++r)
                    Mx = fmaxf(Mx, acc[mt][nt][r]);
            Mx = fmaxf(Mx, __shfl_xor(Mx, 32, 64));
            float Sm = 0.f;
            #pragma unroll
            for (int mt = 0; mt < 4; ++mt)
                #pragma unroll
                for (int r = 0; r < 16; ++r) {
                    const float e = exp2f((acc[mt][nt][r] - Mx) * LOG2E);
                    acc[mt][nt][r] = e;
                    Sm += e;
                }
            Sm += __shfl_xor(Sm, 32, 64);
            const int col = bn + wn * 64 + nt * 32 + l31;
            #pragma unroll
            for (int mt = 0; mt < 4; ++mt) {
                const int row0 = bm + wm * 128 + mt * 32 + h5 * 4;
                #pragma unroll
                for (int rq = 0; rq < 4; ++rq)
                    #pragma unroll
                    for (int rr = 0; rr < 4; ++rr)
                        E[(long)(row0 + rq * 8 + rr) * ldc + col] =
                            (f16)acc[mt][nt][rq * 4 + rr];
            }
            if (lane < 32) {
                const long pidx = ((long)z * 16 + (bm >> 7) + wm) * N + col;
                pm[pidx] = Mx * LOG2E;
                ps[pidx] = Sm;
            }
        }
        return;
    }

    #pragma unroll
    for (int mt = 0; mt < 4; ++mt) {
        #pragma unroll
        for (int nt = 0; nt < 2; ++nt) {
            const int row0 = bm + wm * 128 + mt * 32 + h5 * 4;
            const int col = bn + wn * 64 + nt * 32 + l31;
            if (CMODE == CM_F32 || CMODE == CM_PVS) {
                float* C = (float*)Cv + z * cz;
                #pragma unroll
                for (int rq = 0; rq < 4; ++rq)
                    #pragma unroll
                    for (int rr = 0; rr < 4; ++rr)
                        C[(long)(row0 + rq * 8 + rr) * ldc + col] =
                            acc[mt][nt][rq * 4 + rr];
            } else if (CMODE == CM_F16) {
                f16* C = (f16*)Cv + z * cz;
                #pragma unroll
                for (int rq = 0; rq < 4; ++rq)
                    #pragma unroll
                    for (int rr = 0; rr < 4; ++rr)
                        C[(long)(row0 + rq * 8 + rr) * ldc + col] =
                            (f16)acc[mt][nt][rq * 4 + rr];
            } else if (CMODE == CM_F16T) {
                f16* C = (f16*)Cv + z * cz;
                #pragma unroll
                for (int rq = 0; rq < 4; ++rq) {
                    f16x4 v;
                    #pragma unroll
                    for (int rr = 0; rr < 4; ++rr) v[rr] = (f16)acc[mt][nt][rq * 4 + rr];
                    *(f16x4*)(C + (long)col * ldc + row0 + rq * 8) = v;
                }
            } else { // CM_PROJ2
                const int y = blockIdx.y;
                if (y == 0) {
                    f16* C = (f16*)Cv;
                    #pragma unroll
                    for (int rq = 0; rq < 4; ++rq)
                        #pragma unroll
                        for (int rr = 0; rr < 4; ++rr)
                            C[(long)(row0 + rq * 8 + rr) * 1024 + col] =
                                (f16)acc[mt][nt][rq * 4 + rr];
                } else {
                    f16* C = (f16*)pm;   // vpT [1024][M]
                    #pragma unroll
                    for (int rq = 0; rq < 4; ++rq) {
                        f16x4 v;
                        #pragma unroll
                        for (int rr = 0; rr < 4; ++rr)
                            v[rr] = (f16)acc[mt][nt][rq * 4 + rr];
                        *(f16x4*)(C + (long)col * M + row0 + rq * 8) = v;
                    }
                }
            }
        }
    }
}

// ---------------------------------------------------------------------------
// fused cast: q rows -> f16 + fp32 copy into out[:,0:1024]; k rows -> f16
// ---------------------------------------------------------------------------
__global__ __launch_bounds__(256)
void pack_cast_qk(const float* __restrict__ qin, const float* __restrict__ kin,
                  f16* __restrict__ qp, f16* __restrict__ kp,
                  float* __restrict__ oq, long nquads)
{
    const long i = (long)blockIdx.x * 256 + threadIdx.x;
    if (i >= 2 * nquads) return;
    const int isK = (i >= nquads);
    const long j = isK ? i - nquads : i;
    const long row = j >> 8;
    const int c = (int)(j & 255) * 4;
    const float4 v = isK ? *(const float4*)(kin + row * 1024 + c)
                         : *(const float4*)(qin + row * 1024 + c);
    f16x4 h;
    h[0] = (f16)v.x; h[1] = (f16)v.y; h[2] = (f16)v.z; h[3] = (f16)v.w;
    if (isK) {
        *(f16x4*)(kp + row * 1024 + c) = h;
    } else {
        *(float4*)(oq + row * 2048 + c) = v;
        *(f16x4*)(qp + row * 1024 + c) = h;
    }
}

// plain fp32 [R,1024] -> f16 [R,1024] cast (row-major, no transpose)
__global__ __launch_bounds__(256)
void cast_f16(const float* __restrict__ in, f16* __restrict__ outp, long nquads)
{
    const long i = (long)blockIdx.x * 256 + threadIdx.x;
    if (i >= nquads) return;
    const long row = i >> 8;
    const int c = (int)(i & 255) * 4;
    const float4 v = *(const float4*)(in + row * 1024 + c);
    f16x4 h;
    h[0] = (f16)v.x; h[1] = (f16)v.y; h[2] = (f16)v.z; h[3] = (f16)v.w;
    *(f16x4*)(outp + row * 1024 + c) = h;
}

// ---------------------------------------------------------------------------
// W [1024 d][1024 o] fp32 -> Wt [1024 o][1024 d] f16 (transpose + cast)
// ---------------------------------------------------------------------------
__global__ __launch_bounds__(256)
void pack_W_T(const float* __restrict__ W, f16* __restrict__ Wt)
{
    __shared__ float tile[64][65];
    const int d0 = blockIdx.y * 64, o0 = blockIdx.x * 64;
    const int t = threadIdx.x;
    const int rr = t >> 4, c4 = (t & 15) * 4;
    #pragma unroll
    for (int it = 0; it < 4; ++it) {
        const int r = rr + it * 16;
        const float4 v = *(const float4*)(W + (long)(d0 + r) * 1024 + o0 + c4);
        tile[r][c4] = v.x; tile[r][c4 + 1] = v.y;
        tile[r][c4 + 2] = v.z; tile[r][c4 + 3] = v.w;
    }
    __syncthreads();
    #pragma unroll
    for (int it = 0; it < 4; ++it) {
        const int orow = rr + it * 16;
        f16x4 h;
        #pragma unroll
        for (int j = 0; j < 4; ++j) h[j] = (f16)tile[c4 + j][orow];
        *(f16x4*)(Wt + (long)(o0 + orow) * 1024 + d0 + c4) = h;
    }
}

// ---------------------------------------------------------------------------
// reduce 8 f32 partials [8][1024*1024] -> f16 Gt[1024*1024]
// ---------------------------------------------------------------------------
__global__ __launch_bounds__(256)
void gt_reduce(const float* __restrict__ P, f16* __restrict__ Gt, long nquads)
{
    const long i = (long)blockIdx.x * 256 + threadIdx.x;
    if (i >= nquads) return;
    float4 s = *(const float4*)(P + i * 4);
    #pragma unroll
    for (int z = 1; z < 8; ++z) {
        const float4 v = *(const float4*)(P + (long)z * 1048576 + i * 4);
        s.x += v.x; s.y += v.y; s.z += v.z; s.w += v.w;
    }
    f16x4 h;
    h[0] = (f16)s.x; h[1] = (f16)s.y; h[2] = (f16)s.z; h[3] = (f16)s.w;
    *(f16x4*)(Gt + i * 4) = h;
}

// ---------------------------------------------------------------------------
// merge 16 per-block partials -> f16 scale[z][16][2048] = exp2(pm - L)
// ---------------------------------------------------------------------------
__global__ __launch_bounds__(256)
void softmax_merge16(const float* __restrict__ pm, const float* __restrict__ ps,
                     f16* __restrict__ scale, int nq)
{
    const int idx = blockIdx.x * 256 + threadIdx.x;
    if (idx >= nq) return;
    const int z = idx >> 11, q = idx & 2047;
    const float* pmz = pm + ((long)z * 16) * 2048 + q;
    const float* psz = ps + ((long)z * 16) * 2048 + q;
    float mx = -3.4e38f;
    #pragma unroll
    for (int j = 0; j < 16; ++j) mx = fmaxf(mx, pmz[j * 2048]);
    float s = 0.f;
    #pragma unroll
    for (int j = 0; j < 16; ++j)
        s += psz[j * 2048] * exp2f(pmz[j * 2048] - mx);
    const float L = mx + log2f(s);
    f16* sc = scale + ((long)z * 16) * 2048 + q;
    #pragma unroll
    for (int j = 0; j < 16; ++j)
        sc[j * 2048] = (f16)exp2f(pmz[j * 2048] - L);
}

// ---------------------------------------------------------------------------
__global__ __launch_bounds__(256)
void copy_q_kernel(const float* __restrict__ q, float* __restrict__ out, long n4)
{
    const long idx = (long)blockIdx.x * 256 + threadIdx.x;
    if (idx >= n4) return;
    const long row = idx >> 8;
    const long c4 = idx & 255;
    *(float4*)(&out[row * 2048 + c4 * 4]) =
        *(const float4*)(&q[row * 1024 + c4 * 4]);
}

// ===========================================================================
// fp32 fallback for small workspaces
// ===========================================================================
#define BM 64
#define BN 64
#define BKF 16
template<int opA, int opB>
__global__ __launch_bounds__(256)
void sgemm(const float* __restrict__ A, const float* __restrict__ B,
           float* __restrict__ C,
           int M, int N, int K, int lda, int ldb, int ldc)
{
    __shared__ float As[BKF][BM];
    __shared__ float Bs[BKF][BN];
    const int tid = threadIdx.x;
    const int tx = tid & 15, ty = tid >> 4;
    const int bm = blockIdx.y * BM, bn = blockIdx.x * BN;
    float acc[4][4] = {};
    for (int k0 = 0; k0 < K; k0 += BKF) {
        if (opA == 0) {
            const int row = tid >> 2, kq = (tid & 3) * 4;
            const float4 v = *(const float4*)(A + (long)(bm + row) * lda + (k0 + kq));
            As[kq + 0][row] = v.x; As[kq + 1][row] = v.y;
            As[kq + 2][row] = v.z; As[kq + 3][row] = v.w;
        } else {
            const int kk = tid >> 4, mq = (tid & 15) * 4;
            *(float4*)(&As[kk][mq]) =
                *(const float4*)(A + (long)(k0 + kk) * lda + (bm + mq));
        }
        if (opB == 0) {
            const int kk = tid >> 4, nq = (tid & 15) * 4;
            *(float4*)(&Bs[kk][nq]) =
                *(const float4*)(B + (long)(k0 + kk) * ldb + (bn + nq));
        } else {
            const int row = tid >> 2, kq = (tid & 3) * 4;
            const float4 v = *(const float4*)(B + (long)(bn + row) * ldb + (k0 + kq));
            Bs[kq + 0][row] = v.x; Bs[kq + 1][row] = v.y;
            Bs[kq + 2][row] = v.z; Bs[kq + 3][row] = v.w;
        }
        __syncthreads();
        #pragma unroll
        for (int kk = 0; kk < BKF; ++kk) {
            const float4 a = *(const float4*)(&As[kk][ty * 4]);
            const float4 b = *(const float4*)(&Bs[kk][tx * 4]);
            const float av[4] = {a.x, a.y, a.z, a.w};
            const float bv[4] = {b.x, b.y, b.z, b.w};
            #pragma unroll
            for (int i = 0; i < 4; ++i)
                #pragma unroll
                for (int j = 0; j < 4; ++j)
                    acc[i][j] += av[i] * bv[j];
        }
        __syncthreads();
    }
    #pragma unroll
    for (int i = 0; i < 4; ++i) {
        const float4 v = make_float4(acc[i][0], acc[i][1], acc[i][2], acc[i][3]);
        *(float4*)(&C[(long)(bm + ty * 4 + i) * ldc + (bn + tx * 4)]) = v;
    }
}

__device__ __forceinline__ float wave_reduce_max(float v) {
    #pragma unroll
    for (int off = 1; off < 64; off <<= 1)
        v = fmaxf(v, __shfl_xor(v, off, 64));
    return v;
}
__device__ __forceinline__ float wave_reduce_sum(float v) {
    #pragma unroll
    for (int off = 1; off < 64; off <<= 1)
        v += __shfl_xor(v, off, 64);
    return v;
}

__global__ __launch_bounds__(256)
void softmax_rows2048(float* __restrict__ X)
{
    float* x = X + (long)blockIdx.x * 2048;
    const int tid = threadIdx.x;
    float4 v0 = *(const float4*)(&x[tid * 4]);
    float4 v1 = *(const float4*)(&x[1024 + tid * 4]);
    float m = fmaxf(fmaxf(fmaxf(v0.x, v0.y), fmaxf(v0.z, v0.w)),
                    fmaxf(fmaxf(v1.x, v1.y), fmaxf(v1.z, v1.w)));
    m = wave_reduce_max(m);
    __shared__ float sm[4];
    __shared__ float ss[4];
    const int wid = tid >> 6;
    if ((tid & 63) == 0) sm[wid] = m;
    __syncthreads();
    m = fmaxf(fmaxf(sm[0], sm[1]), fmaxf(sm[2], sm[3]));
    v0.x = expf(v0.x - m); v0.y = expf(v0.y - m);
    v0.z = expf(v0.z - m); v0.w = expf(v0.w - m);
    v1.x = expf(v1.x - m); v1.y = expf(v1.y - m);
    v1.z = expf(v1.z - m); v1.w = expf(v1.w - m);
    float s = (v0.x + v0.y + v0.z + v0.w) + (v1.x + v1.y + v1.z + v1.w);
    s = wave_reduce_sum(s);
    if ((tid & 63) == 0) ss[wid] = s;
    __syncthreads();
    s = ss[0] + ss[1] + ss[2] + ss[3];
    const float inv = 1.0f / s;
    v0.x *= inv; v0.y *= inv; v0.z *= inv; v0.w *= inv;
    v1.x *= inv; v1.y *= inv; v1.z *= inv; v1.w *= inv;
    *(float4*)(&x[tid * 4]) = v0;
    *(float4*)(&x[1024 + tid * 4]) = v1;
}

static void fallback_fp32(const float* q, const float* k, const float* Wq,
                          const float* Wk, const float* Wv, float* out,
                          void* d_ws, hipStream_t stream)
{
    const int S = 2048, D = 1024, O = 1024, B = 8;
    float* qp = (float*)d_ws;
    float* kp = qp + (size_t)S * O;
    float* vp = kp + (size_t)S * O;
    float* attn = vp + (size_t)S * O;
    const long n4 = (long)B * S * D / 4;
    copy_q_kernel<<<dim3((n4 + 255) / 256), 256, 0, stream>>>(q, out, n4);
    const dim3 blk(256);
    const dim3 gproj(O / BN, S / BM), gattn(S / BN, S / BM), gctx(O / BN, S / BM);
    for (int b = 0; b < B; ++b) {
        const float* qb = q + (size_t)b * S * D;
        const float* kb = k + (size_t)b * S * D;
        float* outc = out + (size_t)b * S * 2048 + D;
        sgemm<0, 0><<<gproj, blk, 0, stream>>>(qb, Wq, qp, S, O, D, D, O, O);
        sgemm<0, 0><<<gproj, blk, 0, stream>>>(kb, Wk, kp, S, O, D, D, O, O);
        sgemm<0, 0><<<gproj, blk, 0, stream>>>(kb, Wv, vp, S, O, D, D, O, O);
        sgemm<0, 1><<<gattn, blk, 0, stream>>>(qp, kp, attn, S, S, O, O, O, S);
        softmax_rows2048<<<dim3(S), blk, 0, stream>>>(attn);
        sgemm<1, 0><<<gctx, blk, 0, stream>>>(attn, vp, outc, S, O, S, S, O, 2048);
    }
}

// ===========================================================================
extern "C" void kernel_launch(void* const* d_in, const int* in_sizes, int n_in,
                              void* d_out, int out_size, void* d_ws, size_t ws_size,
                              hipStream_t stream)
{
    const float* q  = (const float*)d_in[0];
    const float* k  = (const float*)d_in[1];
    const float* Wq = (const float*)d_in[2];
    const float* Wk = (const float*)d_in[3];
    const float* Wv = (const float*)d_in[4];
    float* out = (float*)d_out;

    const int B = 8, S = 2048;

    auto need = [](int g) -> size_t {
        const size_t fixed = ((size_t)1024 * 1024 * 2) * 4      // Gt,Wtv,Wq_h,Wk_h
                           + (size_t)8 * 1024 * 1024 * 4;       // Gt partials
        const size_t pkA = (size_t)g * 2048 * 1024 * 2;         // qpack,kpack,qG
        const size_t vpT = (size_t)1024 * g * 2048 * 2;
        const size_t aw  = (size_t)g * 2048 * 2048 * 2;
        const size_t pp  = 2 * (size_t)g * 16 * 2048 * 4 + (size_t)g * 16 * 2048 * 2;
        return fixed + 3 * pkA + vpT + aw + pp + 32 * 256;
    };
    int g = 0;
    for (int cand : {8, 4, 2, 1})
        if (need(cand) <= ws_size) { g = cand; break; }
    if (g == 0) { fallback_fp32(q, k, Wq, Wk, Wv, out, d_ws, stream); return; }

    char* p = (char*)d_ws;
    auto carve = [&](size_t bytes) {
        char* r = p;
        p += (bytes + 255) & ~(size_t)255;
        return r;
    };
    // Gt & Wtv contiguous (B pair for CM_PROJ2); qpack & kpack contiguous.
    f16* Gt   = (f16*)carve((size_t)1024 * 1024 * 2);
    f16* Wtv  = (f16*)carve((size_t)1024 * 1024 * 2);
    f16* Wq_h = (f16*)carve((size_t)1024 * 1024 * 2);
    f16* Wk_h = (f16*)carve((size_t)1024 * 1024 * 2);
    float* Gp = (float*)carve((size_t)8 * 1024 * 1024 * 4);
    const size_t pkAB = (size_t)g * 2048 * 1024 * 2;
    f16* qpack  = (f16*)carve(pkAB);
    f16* kpack  = (f16*)carve(pkAB);
    f16* qG     = (f16*)carve(pkAB);
    f16* vpT    = (f16*)carve((size_t)1024 * g * 2048 * 2);
    f16* attn_w = (f16*)carve((size_t)g * 2048 * 2048 * 2);
    float* pmb  = (float*)carve((size_t)g * 16 * 2048 * 4);
    float* psb  = (float*)carve((size_t)g * 16 * 2048 * 4);
    f16* scb    = (f16*)carve((size_t)g * 16 * 2048 * 2);

    const dim3 blk(256);
    const dim3 blk512(512);

    // --- once: Wv transpose, Wq/Wk casts, Gt = Wk_h @ Wq_h^T (8-way K-split)
    pack_W_T<<<dim3(16, 16), blk, 0, stream>>>(Wv, Wtv);
    cast_f16<<<dim3(1024), blk, 0, stream>>>(Wq, Wq_h, 1024 * 256);
    cast_f16<<<dim3(1024), blk, 0, stream>>>(Wk, Wk_h, 1024 * 256);
    gemm256<CM_F32><<<dim3(16, 1, 8), blk512, 0, stream>>>(
        Wk_h, Wq_h, Gp, 1024, 1024, 128, 1024, 1024, 1024,
        128, 128, (long)1024 * 1024, nullptr, nullptr);
    gt_reduce<<<dim3(1024), blk, 0, stream>>>(Gp, Gt, 1024 * 256);

    const int Mg = g * 2048;
    const long zSS = (long)2048 * 2048;
    const long zSD = (long)2048 * 1024;

    for (int gi = 0; gi < B / g; ++gi) {
        const float* qg = q + (size_t)gi * Mg * 1024;
        const float* kg = k + (size_t)gi * Mg * 1024;
        float* outq = out + (size_t)gi * Mg * 2048;

        const long nquads = (long)Mg * 256;
        pack_cast_qk<<<dim3((2 * nquads + 255) / 256), blk, 0, stream>>>(
            qg, kg, qpack, kpack, outq, nquads);

        // fused projections: y=0 -> qG = qpack@Gt^T ; y=1 -> vpT = kpack@Wtv^T
        const dim3 g1((1024 / 256) * (Mg / 256), 2, 1);
        gemm256<CM_PROJ2><<<g1, blk512, 0, stream>>>(
            qpack, Gt, qG, Mg, 1024, 1024, 1024, 1024, 1024, 0, 0, 0,
            (float*)vpT, nullptr);

        // attnT = kpack @ qG^T per z -> f16 e + partials
        const dim3 g2((2048 / 256) * (2048 / 256), 1, g);
        gemm256<CM_ATTN><<<g2, blk512, 0, stream>>>(
            kpack, qG, attn_w, 2048, 2048, 1024, 1024, 1024, 2048,
            zSD, zSD, zSS, pmb, psb);

        // merge partials -> f16 scale table
        const int nq = g * 2048;
        softmax_merge16<<<dim3((nq + 255) / 256), blk, 0, stream>>>(pmb, psb, scb, nq);

        // context = (e*scale) @ vpT^T -> out cols 1024..2047
        float* outg = out + (size_t)gi * Mg * 2048 + 1024;
        const dim3 g3((1024 / 256) * (2048 / 256), 1, g);
        gemm256<CM_PVS><<<g3, blk512, 0, stream>>>(
            attn_w, vpT, outg, 2048, 1024, 2048, 2048, Mg, 2048,
            zSS, 2048, zSS, nullptr, (float*)scb);
    }
}